// Round 1
// baseline (6324.618 us; speedup 1.0000x reference)
//
#include <hip/hip_runtime.h>
#include <math.h>

#define TT 1024
#define VV 32000
#define EE 1024
#define NH 16
#define NKVH 4
#define DHEAD 64
#define NKV 256      // NKVH*DHEAD
#define FF 4096
#define LEPS 1e-5f

// ---------------- block reduction helpers (blockDim.x == 256) ----------------
__device__ __forceinline__ float block_reduce_sum(float v, float* red) {
    int tid = threadIdx.x;
    red[tid] = v; __syncthreads();
    for (int off = 128; off > 0; off >>= 1) {
        if (tid < off) red[tid] += red[tid + off];
        __syncthreads();
    }
    float r = red[0];
    __syncthreads();
    return r;
}
__device__ __forceinline__ float block_reduce_max(float v, float* red) {
    int tid = threadIdx.x;
    red[tid] = v; __syncthreads();
    for (int off = 128; off > 0; off >>= 1) {
        if (tid < off) red[tid] = fmaxf(red[tid], red[tid + off]);
        __syncthreads();
    }
    float r = red[0];
    __syncthreads();
    return r;
}

// ---------------- embedding gather ----------------
__global__ __launch_bounds__(256) void gather_kernel(const float* __restrict__ embed,
                                                     const int* __restrict__ idx,
                                                     float* __restrict__ x) {
    int t = blockIdx.x;
    long r = idx[t];
    const float4* src = (const float4*)(embed + r * EE);
    float4* dst = (float4*)(x + (long)t * EE);
    for (int i = threadIdx.x; i < EE / 4; i += 256) dst[i] = src[i];
}

// ---------------- layernorm (one block per row) ----------------
__global__ __launch_bounds__(256) void ln_kernel(const float* __restrict__ x,
                                                 const float* __restrict__ g,
                                                 const float* __restrict__ b,
                                                 float* __restrict__ out) {
    __shared__ float red[256];
    int t = blockIdx.x;
    const float* xr = x + (long)t * EE;
    float s = 0.f;
    for (int i = threadIdx.x; i < EE; i += 256) s += xr[i];
    float mu = block_reduce_sum(s, red) * (1.f / EE);
    float vs = 0.f;
    for (int i = threadIdx.x; i < EE; i += 256) { float d = xr[i] - mu; vs += d * d; }
    float var = block_reduce_sum(vs, red) * (1.f / EE);
    float rstd = rsqrtf(var + LEPS);
    float* orow = out + (long)t * EE;
    for (int i = threadIdx.x; i < EE; i += 256)
        orow[i] = (xr[i] - mu) * rstd * g[i] + b[i];
}

// ---------------- RoPE (first 32 dims of each head), in-place ----------------
__global__ __launch_bounds__(256) void rope_kernel(float* __restrict__ q, int nheads, int rowstride) {
    int idx = blockIdx.x * 256 + threadIdx.x;
    int total = TT * nheads * 16;
    if (idx >= total) return;
    int i = idx & 15;
    int h = (idx >> 4) % nheads;
    int t = idx / (16 * nheads);
    // theta_i = 10000^(-i/16)
    float theta = expf(-(float)i * (9.210340371976184f / 16.f)); // ln(10000)=9.2103...
    float ang = (float)t * theta;
    float c = cosf(ang), s = sinf(ang);
    float* p = q + (long)t * rowstride + h * DHEAD;
    float a = p[i], bb = p[i + 16];
    p[i]      = a * c - bb * s;
    p[i + 16] = bb * c + a * s;
}

// ---------------- tiled GEMM: C[M,N] = A[M,K] @ B  (opt. B^T, gelu, +=) ------
// TRANS_B=false: B is K x N row-major.  TRANS_B=true: B is N x K row-major.
template<bool TRANS_B, bool GELU_ACT, bool ADD>
__global__ __launch_bounds__(256) void gemm_kernel(const float* __restrict__ A,
                                                   const float* __restrict__ B,
                                                   float* __restrict__ C,
                                                   int M, int N, int K) {
    __shared__ float As[64][17];
    __shared__ float Bs[16][65];
    int tid = threadIdx.x;
    int row0 = blockIdx.y * 64, col0 = blockIdx.x * 64;
    int tx = tid & 15, ty = tid >> 4;
    float acc[4][4] = {};
    for (int k0 = 0; k0 < K; k0 += 16) {
        #pragma unroll
        for (int u = 0; u < 4; ++u) {
            int idx = u * 256 + tid;
            int ai = idx >> 4, aj = idx & 15;           // A tile 64x16
            As[ai][aj] = A[(long)(row0 + ai) * K + k0 + aj];
            if (TRANS_B) {
                int bi = idx & 15, bj = idx >> 4;       // k, n
                Bs[bi][bj] = B[(long)(col0 + bj) * K + k0 + bi];
            } else {
                int bi = idx >> 6, bj = idx & 63;       // k, n
                Bs[bi][bj] = B[(long)(k0 + bi) * N + col0 + bj];
            }
        }
        __syncthreads();
        #pragma unroll
        for (int kk = 0; kk < 16; ++kk) {
            float a[4], b[4];
            #pragma unroll
            for (int m = 0; m < 4; ++m) a[m] = As[ty * 4 + m][kk];
            #pragma unroll
            for (int n = 0; n < 4; ++n) b[n] = Bs[kk][tx * 4 + n];
            #pragma unroll
            for (int m = 0; m < 4; ++m)
                #pragma unroll
                for (int n = 0; n < 4; ++n) acc[m][n] += a[m] * b[n];
        }
        __syncthreads();
    }
    #pragma unroll
    for (int m = 0; m < 4; ++m) {
        int r = row0 + ty * 4 + m;
        #pragma unroll
        for (int n = 0; n < 4; ++n) {
            int c = col0 + tx * 4 + n;
            float val = acc[m][n];
            if (GELU_ACT) val = 0.5f * val * (1.f + erff(val * 0.70710678118654752f));
            if (ADD) C[(long)r * N + c] += val;
            else     C[(long)r * N + c] = val;
        }
    }
}

// ---------------- attention: one block per (head, query t) ----------------
__global__ __launch_bounds__(256) void attn_kernel(const float* __restrict__ q,
                                                   const float* __restrict__ k,
                                                   const float* __restrict__ v,
                                                   const float* __restrict__ gate,
                                                   float* __restrict__ y) {
    __shared__ float qs[64];
    __shared__ float sc[TT];
    __shared__ float red[256];
    __shared__ float psum[4][64];
    int h = blockIdx.x;
    int t = blockIdx.y;
    int tid = threadIdx.x;
    int kvh = h >> 2;   // H/HKV = 4

    if (tid < 64) qs[tid] = q[(long)t * EE + h * DHEAD + tid];
    __syncthreads();

    float lmax = -INFINITY;
    for (int s = tid; s <= t; s += 256) {
        const float* kr = k + (long)s * NKV + kvh * DHEAD;
        float d = 0.f;
        #pragma unroll 8
        for (int j = 0; j < DHEAD; ++j) d += qs[j] * kr[j];
        d *= 0.125f;   // 1/sqrt(64)
        sc[s] = d;
        lmax = fmaxf(lmax, d);
    }
    float mx = block_reduce_max(lmax, red);

    float lsum = 0.f;
    for (int s = tid; s <= t; s += 256) {
        float w = expf(sc[s] - mx);
        sc[s] = w;
        lsum += w;
    }
    float sum = block_reduce_sum(lsum, red);
    float inv = 1.f / sum;
    float thr = 1.f / (1.f + expf(-gate[h]));

    for (int s = tid; s <= t; s += 256) {
        float p = sc[s] * inv;
        sc[s] = (p >= thr) ? p : 0.f;
    }
    __syncthreads();

    int d = tid & 63, chunk = tid >> 6;
    float acc = 0.f;
    for (int s = chunk; s <= t; s += 4)
        acc += sc[s] * v[(long)s * NKV + kvh * DHEAD + d];
    psum[chunk][d] = acc;
    __syncthreads();
    if (tid < 64)
        y[(long)t * EE + h * DHEAD + tid] =
            psum[0][tid] + psum[1][tid] + psum[2][tid] + psum[3][tid];
}

// ---------------- loss ----------------
__global__ __launch_bounds__(256) void row_loss_kernel(const float* __restrict__ logits,
                                                       const int* __restrict__ targets,
                                                       float* __restrict__ row_loss) {
    __shared__ float red[256];
    int t = blockIdx.x;
    const float* lr = logits + (long)t * VV;
    float lmax = -INFINITY;
    for (int i = threadIdx.x; i < VV; i += 256) lmax = fmaxf(lmax, lr[i]);
    float mx = block_reduce_max(lmax, red);
    float ls = 0.f;
    for (int i = threadIdx.x; i < VV; i += 256) ls += expf(lr[i] - mx);
    float sum = block_reduce_sum(ls, red);
    if (threadIdx.x == 0)
        row_loss[t] = logf(sum) + mx - lr[targets[t]];
}

__global__ __launch_bounds__(256) void final_loss_kernel(const float* __restrict__ row_loss,
                                                         float* __restrict__ out) {
    __shared__ float red[256];
    float s = 0.f;
    for (int i = threadIdx.x; i < TT; i += 256) s += row_loss[i];
    float tot = block_reduce_sum(s, red);
    if (threadIdx.x == 0) out[0] = tot * (1.f / TT);
}

// ---------------- host orchestration ----------------
extern "C" void kernel_launch(void* const* d_in, const int* in_sizes, int n_in,
                              void* d_out, int out_size, void* d_ws, size_t ws_size,
                              hipStream_t stream) {
    const float* embed = (const float*)d_in[0];
    const float* ln1_g = (const float*)d_in[1];
    const float* ln1_b = (const float*)d_in[2];
    const float* Wq    = (const float*)d_in[3];
    const float* Wk    = (const float*)d_in[4];
    const float* Wv    = (const float*)d_in[5];
    const float* Wo    = (const float*)d_in[6];
    const float* gate  = (const float*)d_in[7];
    const float* ln2_g = (const float*)d_in[8];
    const float* ln2_b = (const float*)d_in[9];
    const float* W1    = (const float*)d_in[10];
    const float* W2    = (const float*)d_in[11];
    const float* lnf_g = (const float*)d_in[12];
    const float* lnf_b = (const float*)d_in[13];
    const int*   idx   = (const int*)d_in[14];
    const int*   tgt   = (const int*)d_in[15];
    float* out = (float*)d_out;

    float* ws = (float*)d_ws;
    float* x    = ws;               // T*E
    float* xn   = x   + TT * EE;    // T*E
    float* q    = xn  + TT * EE;    // T*E
    float* kbuf = q   + TT * EE;    // T*NKV
    float* vbuf = kbuf + TT * NKV;  // T*NKV
    float* y    = vbuf + TT * NKV;  // T*E
    float* h1   = y   + TT * EE;    // T*FF
    float* rls  = h1  + TT * FF;    // T

    gather_kernel<<<TT, 256, 0, stream>>>(embed, idx, x);

    for (int r = 0; r < 2; ++r) {
        for (int l = 0; l < 2; ++l) {
            const float* wq = Wq + (long)l * EE * EE;
            const float* wk = Wk + (long)l * EE * NKV;
            const float* wv = Wv + (long)l * EE * NKV;
            const float* wo = Wo + (long)l * EE * EE;
            const float* w1 = W1 + (long)l * EE * FF;
            const float* w2 = W2 + (long)l * FF * EE;

            ln_kernel<<<TT, 256, 0, stream>>>(x, ln1_g + l * EE, ln1_b + l * EE, xn);
            gemm_kernel<false, false, false><<<dim3(EE / 64, TT / 64), 256, 0, stream>>>(xn, wq, q, TT, EE, EE);
            gemm_kernel<false, false, false><<<dim3(NKV / 64, TT / 64), 256, 0, stream>>>(xn, wk, kbuf, TT, NKV, EE);
            gemm_kernel<false, false, false><<<dim3(NKV / 64, TT / 64), 256, 0, stream>>>(xn, wv, vbuf, TT, NKV, EE);
            rope_kernel<<<(TT * NH * 16 + 255) / 256, 256, 0, stream>>>(q, NH, EE);
            rope_kernel<<<(TT * NKVH * 16 + 255) / 256, 256, 0, stream>>>(kbuf, NKVH, NKV);
            attn_kernel<<<dim3(NH, TT), 256, 0, stream>>>(q, kbuf, vbuf, gate + l * NH, y);
            gemm_kernel<false, false, true><<<dim3(EE / 64, TT / 64), 256, 0, stream>>>(y, wo, x, TT, EE, EE);

            ln_kernel<<<TT, 256, 0, stream>>>(x, ln2_g + l * EE, ln2_b + l * EE, xn);
            gemm_kernel<false, true, false><<<dim3(FF / 64, TT / 64), 256, 0, stream>>>(xn, w1, h1, TT, FF, EE);
            gemm_kernel<false, false, true><<<dim3(EE / 64, TT / 64), 256, 0, stream>>>(h1, w2, x, TT, EE, FF);
        }
    }

    ln_kernel<<<TT, 256, 0, stream>>>(x, lnf_g, lnf_b, xn);
    // logits = xn @ embed^T  (embed is V x E row-major -> TRANS_B)
    gemm_kernel<true, false, false><<<dim3(VV / 64, TT / 64), 256, 0, stream>>>(xn, embed, out, TT, VV, EE);

    row_loss_kernel<<<TT, 256, 0, stream>>>(out, tgt, rls);
    final_loss_kernel<<<1, 256, 0, stream>>>(rls, out + (long)TT * VV);
}

// Round 2
// 3039.062 us; speedup vs baseline: 2.0811x; 2.0811x over previous
//
#include <hip/hip_runtime.h>
#include <math.h>

#define TT 1024
#define VV 32000
#define EE 1024
#define NH 16
#define NKVH 4
#define DHEAD 64
#define QKVN 1536    // E + 2*NKVH*DHEAD
#define FF 4096
#define LEPS 1e-5f

typedef __attribute__((ext_vector_type(8))) short short8;
typedef __attribute__((ext_vector_type(4))) float floatx4;

__device__ __forceinline__ ushort f2bf(float f) {
    unsigned x = __float_as_uint(f);
    unsigned r = (x + 0x7fffu + ((x >> 16) & 1u)) >> 16;
    return (ushort)r;
}

// ---------------- block reduction helpers (blockDim.x == 256) ----------------
__device__ __forceinline__ float block_reduce_sum(float v, float* red) {
    int tid = threadIdx.x;
    red[tid] = v; __syncthreads();
    for (int off = 128; off > 0; off >>= 1) {
        if (tid < off) red[tid] += red[tid + off];
        __syncthreads();
    }
    float r = red[0];
    __syncthreads();
    return r;
}
__device__ __forceinline__ float block_reduce_max(float v, float* red) {
    int tid = threadIdx.x;
    red[tid] = v; __syncthreads();
    for (int off = 128; off > 0; off >>= 1) {
        if (tid < off) red[tid] = fmaxf(red[tid], red[tid + off]);
        __syncthreads();
    }
    float r = red[0];
    __syncthreads();
    return r;
}

// ---------------- prep: fp32 -> bf16 flat convert (embed) ----------------
__global__ __launch_bounds__(256) void convert_bf16_kernel(const float* __restrict__ src,
                                                           ushort* __restrict__ dst, long n4) {
    long i = (long)blockIdx.x * 256 + threadIdx.x;
    if (i >= n4) return;
    float4 f = ((const float4*)src)[i];
    ushort u[4] = { f2bf(f.x), f2bf(f.y), f2bf(f.z), f2bf(f.w) };
    ((uint2*)dst)[i] = *(uint2*)u;
}

// ---------------- prep: W (K x N fp32) -> dst (N x K bf16) ----------------
__global__ __launch_bounds__(256) void transpose_bf16_kernel(const float* __restrict__ W,
                                                             ushort* __restrict__ dst,
                                                             int N, int K) {
    __shared__ float tile[32][33];
    int n0 = blockIdx.x * 32, k0 = blockIdx.y * 32;
    int tx = threadIdx.x & 31, ty = threadIdx.x >> 5;
    for (int i = ty; i < 32; i += 8) tile[i][tx] = W[(long)(k0 + i) * N + n0 + tx];
    __syncthreads();
    for (int i = ty; i < 32; i += 8)
        dst[(long)(n0 + i) * K + k0 + tx] = f2bf(tile[tx][i]);
}

// ---------------- embedding gather ----------------
__global__ __launch_bounds__(256) void gather_kernel(const float* __restrict__ embed,
                                                     const int* __restrict__ idx,
                                                     float* __restrict__ x) {
    int t = blockIdx.x;
    long r = idx[t];
    const float4* src = (const float4*)(embed + r * EE);
    float4* dst = (float4*)(x + (long)t * EE);
    for (int i = threadIdx.x; i < EE / 4; i += 256) dst[i] = src[i];
}

// ---------------- layernorm (one block per row) -> bf16 out ----------------
__global__ __launch_bounds__(256) void ln_kernel(const float* __restrict__ x,
                                                 const float* __restrict__ g,
                                                 const float* __restrict__ b,
                                                 ushort* __restrict__ out) {
    __shared__ float red[256];
    int t = blockIdx.x;
    const float* xr = x + (long)t * EE;
    float s = 0.f;
    for (int i = threadIdx.x; i < EE; i += 256) s += xr[i];
    float mu = block_reduce_sum(s, red) * (1.f / EE);
    float vs = 0.f;
    for (int i = threadIdx.x; i < EE; i += 256) { float d = xr[i] - mu; vs += d * d; }
    float var = block_reduce_sum(vs, red) * (1.f / EE);
    float rstd = rsqrtf(var + LEPS);
    ushort* orow = out + (long)t * EE;
    for (int i = threadIdx.x; i < EE; i += 256)
        orow[i] = f2bf((xr[i] - mu) * rstd * g[i] + b[i]);
}

// ---------------- RoPE (first 32 dims of each head), in-place fp32 ----------
__global__ __launch_bounds__(256) void rope_kernel(float* __restrict__ q, int nheads, int rowstride) {
    int idx = blockIdx.x * 256 + threadIdx.x;
    int total = TT * nheads * 16;
    if (idx >= total) return;
    int i = idx & 15;
    int h = (idx >> 4) % nheads;
    int t = idx / (16 * nheads);
    float theta = expf(-(float)i * (9.210340371976184f / 16.f));
    float ang = (float)t * theta;
    float c = cosf(ang), s = sinf(ang);
    float* p = q + (long)t * rowstride + h * DHEAD;
    float a = p[i], bb = p[i + 16];
    p[i]      = a * c - bb * s;
    p[i + 16] = bb * c + a * s;
}

// ---------------- bf16 MFMA GEMM: C[M,N] = A[M,K] @ Bt[N,K]^T ----------------
// m97 structure: 128x128 tile, BK=32, 4 waves each 64x64 (4x4 16x16x32 frags),
// global_load_lds width-16 staging into unpadded 64B LDS rows.
template<bool GELU_ACT, bool ADD, bool OUTBF>
__global__ __launch_bounds__(256) void gemm_bf16(const ushort* __restrict__ A,
                                                 const ushort* __restrict__ B,
                                                 void* __restrict__ Cv,
                                                 int M, int N, int K) {
    __shared__ char lds[16384];   // A tile 8KB @0, B tile 8KB @8192
    const int tid = threadIdx.x;
    const int lane = tid & 63;
    const int w = tid >> 6;
    const int row0 = blockIdx.y * 128, col0 = blockIdx.x * 128;

    const char* ga[2]; const char* gb[2];
    char* la[2]; char* lb[2];
    #pragma unroll
    for (int r = 0; r < 2; ++r) {
        int c = r * 256 + tid;                 // 16B chunk id, 512 per tile
        ga[r] = (const char*)A + ((long)(row0 + (c >> 2)) * K) * 2 + (c & 3) * 16;
        gb[r] = (const char*)B + ((long)(col0 + (c >> 2)) * K) * 2 + (c & 3) * 16;
        int wc = r * 256 + w * 64;             // wave-uniform chunk base
        la[r] = lds + wc * 16;
        lb[r] = lds + 8192 + wc * 16;
    }

    floatx4 acc[4][4];
    #pragma unroll
    for (int i = 0; i < 4; ++i)
        #pragma unroll
        for (int j = 0; j < 4; ++j) acc[i][j] = {0.f, 0.f, 0.f, 0.f};

    const int mbase = (w >> 1) * 64;
    const int nbase = (w & 1) * 64;
    const int lr = lane & 15;
    const int ko = (lane >> 4) * 16;           // byte offset of k-group in 64B row

    for (int k0 = 0; k0 < K; k0 += 32) {
        #pragma unroll
        for (int r = 0; r < 2; ++r) {
            __builtin_amdgcn_global_load_lds(
                (const __attribute__((address_space(1))) void*)ga[r],
                (__attribute__((address_space(3))) void*)la[r], 16, 0, 0);
            __builtin_amdgcn_global_load_lds(
                (const __attribute__((address_space(1))) void*)gb[r],
                (__attribute__((address_space(3))) void*)lb[r], 16, 0, 0);
            ga[r] += 64; gb[r] += 64;
        }
        __syncthreads();
        short8 af[4], bfr[4];
        #pragma unroll
        for (int i = 0; i < 4; ++i)
            af[i] = *(const short8*)(lds + (mbase + i * 16 + lr) * 64 + ko);
        #pragma unroll
        for (int j = 0; j < 4; ++j)
            bfr[j] = *(const short8*)(lds + 8192 + (nbase + j * 16 + lr) * 64 + ko);
        #pragma unroll
        for (int i = 0; i < 4; ++i)
            #pragma unroll
            for (int j = 0; j < 4; ++j)
                acc[i][j] = __builtin_amdgcn_mfma_f32_16x16x32_bf16(af[i], bfr[j], acc[i][j], 0, 0, 0);
        __syncthreads();
    }

    const int orow = (lane >> 4) * 4;
    const int ocol = lane & 15;
    #pragma unroll
    for (int i = 0; i < 4; ++i) {
        #pragma unroll
        for (int j = 0; j < 4; ++j) {
            #pragma unroll
            for (int r = 0; r < 4; ++r) {
                long off = (long)(row0 + mbase + i * 16 + orow + r) * N
                         + (col0 + nbase + j * 16 + ocol);
                float v = acc[i][j][r];
                if (GELU_ACT) v = 0.5f * v * (1.f + erff(v * 0.70710678118654752f));
                if (OUTBF) {
                    ((ushort*)Cv)[off] = f2bf(v);
                } else {
                    float* C = (float*)Cv;
                    if (ADD) C[off] += v; else C[off] = v;
                }
            }
        }
    }
}

// ---------------- attention: one block per (head, query t) ----------------
// qkv layout per row t: [q(1024) | k(256) | v(256)] fp32, stride 1536
__global__ __launch_bounds__(256) void attn_kernel(const float* __restrict__ qkv,
                                                   const float* __restrict__ gate,
                                                   ushort* __restrict__ y) {
    __shared__ float4 qs4[16];
    __shared__ float sc[TT];
    __shared__ float red[256];
    __shared__ float psum[4][64];
    int h = blockIdx.x;
    int t = blockIdx.y;
    int tid = threadIdx.x;
    int kvh = h >> 2;

    if (tid < 16) qs4[tid] = ((const float4*)(qkv + (long)t * QKVN + h * DHEAD))[tid];
    __syncthreads();

    float lmax = -INFINITY;
    for (int s = tid; s <= t; s += 256) {
        const float4* kr = (const float4*)(qkv + (long)s * QKVN + EE + kvh * DHEAD);
        float d = 0.f;
        #pragma unroll
        for (int j = 0; j < 16; ++j) {
            float4 a = qs4[j], b = kr[j];
            d += a.x * b.x + a.y * b.y + a.z * b.z + a.w * b.w;
        }
        d *= 0.125f;
        sc[s] = d;
        lmax = fmaxf(lmax, d);
    }
    float mx = block_reduce_max(lmax, red);

    float lsum = 0.f;
    for (int s = tid; s <= t; s += 256) {
        float wv = expf(sc[s] - mx);
        sc[s] = wv;
        lsum += wv;
    }
    float sum = block_reduce_sum(lsum, red);
    float inv = 1.f / sum;
    float thr = 1.f / (1.f + expf(-gate[h]));

    for (int s = tid; s <= t; s += 256) {
        float p = sc[s] * inv;
        sc[s] = (p >= thr) ? p : 0.f;
    }
    __syncthreads();

    int d = tid & 63, chunk = tid >> 6;
    float acc = 0.f;
    for (int s = chunk; s <= t; s += 4)
        acc += sc[s] * qkv[(long)s * QKVN + EE + NKVH * DHEAD + kvh * DHEAD + d];
    psum[chunk][d] = acc;
    __syncthreads();
    if (tid < 64)
        y[(long)t * EE + h * DHEAD + tid] =
            f2bf(psum[0][tid] + psum[1][tid] + psum[2][tid] + psum[3][tid]);
}

// ---------------- loss ----------------
__global__ __launch_bounds__(256) void row_loss_kernel(const float* __restrict__ logits,
                                                       const int* __restrict__ targets,
                                                       float* __restrict__ row_loss) {
    __shared__ float red[256];
    int t = blockIdx.x;
    const float* lr = logits + (long)t * VV;
    float lmax = -INFINITY;
    for (int i = threadIdx.x; i < VV; i += 256) lmax = fmaxf(lmax, lr[i]);
    float mx = block_reduce_max(lmax, red);
    float ls = 0.f;
    for (int i = threadIdx.x; i < VV; i += 256) ls += expf(lr[i] - mx);
    float sum = block_reduce_sum(ls, red);
    if (threadIdx.x == 0)
        row_loss[t] = logf(sum) + mx - lr[targets[t]];
}

__global__ __launch_bounds__(256) void final_loss_kernel(const float* __restrict__ row_loss,
                                                         float* __restrict__ out) {
    __shared__ float red[256];
    float s = 0.f;
    for (int i = threadIdx.x; i < TT; i += 256) s += row_loss[i];
    float tot = block_reduce_sum(s, red);
    if (threadIdx.x == 0) out[0] = tot * (1.f / TT);
}

// ---------------- host orchestration ----------------
extern "C" void kernel_launch(void* const* d_in, const int* in_sizes, int n_in,
                              void* d_out, int out_size, void* d_ws, size_t ws_size,
                              hipStream_t stream) {
    const float* embed = (const float*)d_in[0];
    const float* ln1_g = (const float*)d_in[1];
    const float* ln1_b = (const float*)d_in[2];
    const float* Wq    = (const float*)d_in[3];
    const float* Wk    = (const float*)d_in[4];
    const float* Wv    = (const float*)d_in[5];
    const float* Wo    = (const float*)d_in[6];
    const float* gate  = (const float*)d_in[7];
    const float* ln2_g = (const float*)d_in[8];
    const float* ln2_b = (const float*)d_in[9];
    const float* W1    = (const float*)d_in[10];
    const float* W2    = (const float*)d_in[11];
    const float* lnf_g = (const float*)d_in[12];
    const float* lnf_b = (const float*)d_in[13];
    const int*   idx   = (const int*)d_in[14];
    const int*   tgt   = (const int*)d_in[15];
    float* out = (float*)d_out;

    char* p = (char*)d_ws;
    float*  x     = (float*)p;  p += (long)TT * EE * 4;
    ushort* xn    = (ushort*)p; p += (long)TT * EE * 2;
    float*  qkv   = (float*)p;  p += (long)TT * QKVN * 4;
    ushort* y     = (ushort*)p; p += (long)TT * EE * 2;
    ushort* h1    = (ushort*)p; p += (long)TT * FF * 2;
    float*  rls   = (float*)p;  p += (long)TT * 4;
    ushort* wqkvT = (ushort*)p; p += (long)2 * QKVN * EE * 2;
    ushort* woT   = (ushort*)p; p += (long)2 * EE * EE * 2;
    ushort* w1T   = (ushort*)p; p += (long)2 * FF * EE * 2;
    ushort* w2T   = (ushort*)p; p += (long)2 * EE * FF * 2;
    ushort* embB  = (ushort*)p; p += (long)VV * EE * 2;

    // ---- prep: bf16 conversions / transposes (same work every call) ----
    convert_bf16_kernel<<<((long)VV * EE / 4 + 255) / 256, 256, 0, stream>>>(embed, embB, (long)VV * EE / 4);
    for (int l = 0; l < 2; ++l) {
        transpose_bf16_kernel<<<dim3(EE / 32, EE / 32), 256, 0, stream>>>(
            Wq + (long)l * EE * EE, wqkvT + (long)l * QKVN * EE, EE, EE);
        transpose_bf16_kernel<<<dim3(NKVH * DHEAD / 32, EE / 32), 256, 0, stream>>>(
            Wk + (long)l * EE * NKVH * DHEAD, wqkvT + (long)l * QKVN * EE + (long)EE * EE, NKVH * DHEAD, EE);
        transpose_bf16_kernel<<<dim3(NKVH * DHEAD / 32, EE / 32), 256, 0, stream>>>(
            Wv + (long)l * EE * NKVH * DHEAD, wqkvT + (long)l * QKVN * EE + (long)(EE + NKVH * DHEAD) * EE, NKVH * DHEAD, EE);
        transpose_bf16_kernel<<<dim3(EE / 32, EE / 32), 256, 0, stream>>>(
            Wo + (long)l * EE * EE, woT + (long)l * EE * EE, EE, EE);
        transpose_bf16_kernel<<<dim3(FF / 32, EE / 32), 256, 0, stream>>>(
            W1 + (long)l * EE * FF, w1T + (long)l * FF * EE, FF, EE);
        transpose_bf16_kernel<<<dim3(EE / 32, FF / 32), 256, 0, stream>>>(
            W2 + (long)l * FF * EE, w2T + (long)l * EE * FF, EE, FF);
    }

    gather_kernel<<<TT, 256, 0, stream>>>(embed, idx, x);

    for (int r = 0; r < 2; ++r) {
        for (int l = 0; l < 2; ++l) {
            ln_kernel<<<TT, 256, 0, stream>>>(x, ln1_g + l * EE, ln1_b + l * EE, xn);
            gemm_bf16<false, false, false><<<dim3(QKVN / 128, TT / 128), 256, 0, stream>>>(
                xn, wqkvT + (long)l * QKVN * EE, qkv, TT, QKVN, EE);
            rope_kernel<<<(TT * NH * 16 + 255) / 256, 256, 0, stream>>>(qkv, NH, QKVN);
            rope_kernel<<<(TT * NKVH * 16 + 255) / 256, 256, 0, stream>>>(qkv + EE, NKVH, QKVN);
            attn_kernel<<<dim3(NH, TT), 256, 0, stream>>>(qkv, gate + l * NH, y);
            gemm_bf16<false, true, false><<<dim3(EE / 128, TT / 128), 256, 0, stream>>>(
                y, woT + (long)l * EE * EE, x, TT, EE, EE);

            ln_kernel<<<TT, 256, 0, stream>>>(x, ln2_g + l * EE, ln2_b + l * EE, xn);
            gemm_bf16<true, false, true><<<dim3(FF / 128, TT / 128), 256, 0, stream>>>(
                xn, w1T + (long)l * FF * EE, h1, TT, FF, EE);
            gemm_bf16<false, true, false><<<dim3(EE / 128, TT / 128), 256, 0, stream>>>(
                h1, w2T + (long)l * EE * FF, x, TT, EE, FF);
        }
    }

    ln_kernel<<<TT, 256, 0, stream>>>(x, lnf_g, lnf_b, xn);
    gemm_bf16<false, false, false><<<dim3(VV / 128, TT / 128), 256, 0, stream>>>(
        xn, embB, out, TT, VV, EE);

    row_loss_kernel<<<TT, 256, 0, stream>>>(out, tgt, rls);
    final_loss_kernel<<<1, 256, 0, stream>>>(rls, out + (long)TT * VV);
}

// Round 3
// 1607.504 us; speedup vs baseline: 3.9344x; 1.8905x over previous
//
#include <hip/hip_runtime.h>
#include <math.h>

#define TT 1024
#define VV 32000
#define EE 1024
#define NH 16
#define NKVH 4
#define DHEAD 64
#define QKVN 1536    // E + 2*NKVH*DHEAD
#define FF 4096
#define LEPS 1e-5f

typedef __attribute__((ext_vector_type(8))) short short8;
typedef __attribute__((ext_vector_type(4))) float floatx4;

__device__ __forceinline__ ushort f2bf(float f) {
    unsigned x = __float_as_uint(f);
    unsigned r = (x + 0x7fffu + ((x >> 16) & 1u)) >> 16;
    return (ushort)r;
}
__device__ __forceinline__ float bf2f(ushort u) {
    return __uint_as_float(((unsigned)u) << 16);
}

// ---------------- block reduction helpers (blockDim.x == 256) ----------------
__device__ __forceinline__ float block_reduce_sum(float v, float* red) {
    int tid = threadIdx.x;
    red[tid] = v; __syncthreads();
    for (int off = 128; off > 0; off >>= 1) {
        if (tid < off) red[tid] += red[tid + off];
        __syncthreads();
    }
    float r = red[0];
    __syncthreads();
    return r;
}
__device__ __forceinline__ float block_reduce_max(float v, float* red) {
    int tid = threadIdx.x;
    red[tid] = v; __syncthreads();
    for (int off = 128; off > 0; off >>= 1) {
        if (tid < off) red[tid] = fmaxf(red[tid], red[tid + off]);
        __syncthreads();
    }
    float r = red[0];
    __syncthreads();
    return r;
}

// ---------------- prep: fp32 -> bf16 flat convert (embed) ----------------
__global__ __launch_bounds__(256) void convert_bf16_kernel(const float* __restrict__ src,
                                                           ushort* __restrict__ dst, long n4) {
    long i = (long)blockIdx.x * 256 + threadIdx.x;
    if (i >= n4) return;
    float4 f = ((const float4*)src)[i];
    ushort u[4] = { f2bf(f.x), f2bf(f.y), f2bf(f.z), f2bf(f.w) };
    ((uint2*)dst)[i] = *(uint2*)u;
}

// ---------------- prep: W (K x N fp32) -> dst (N x K bf16) ----------------
__global__ __launch_bounds__(256) void transpose_bf16_kernel(const float* __restrict__ W,
                                                             ushort* __restrict__ dst,
                                                             int N, int K) {
    __shared__ float tile[32][33];
    int n0 = blockIdx.x * 32, k0 = blockIdx.y * 32;
    int tx = threadIdx.x & 31, ty = threadIdx.x >> 5;
    for (int i = ty; i < 32; i += 8) tile[i][tx] = W[(long)(k0 + i) * N + n0 + tx];
    __syncthreads();
    for (int i = ty; i < 32; i += 8)
        dst[(long)(n0 + i) * K + k0 + tx] = f2bf(tile[tx][i]);
}

// ---------------- embedding gather ----------------
__global__ __launch_bounds__(256) void gather_kernel(const float* __restrict__ embed,
                                                     const int* __restrict__ idx,
                                                     float* __restrict__ x) {
    int t = blockIdx.x;
    long r = idx[t];
    const float4* src = (const float4*)(embed + r * EE);
    float4* dst = (float4*)(x + (long)t * EE);
    for (int i = threadIdx.x; i < EE / 4; i += 256) dst[i] = src[i];
}

// ---------------- layernorm (one block per row) -> bf16 out ----------------
__global__ __launch_bounds__(256) void ln_kernel(const float* __restrict__ x,
                                                 const float* __restrict__ g,
                                                 const float* __restrict__ b,
                                                 ushort* __restrict__ out) {
    __shared__ float red[256];
    int t = blockIdx.x;
    const float* xr = x + (long)t * EE;
    float s = 0.f;
    for (int i = threadIdx.x; i < EE; i += 256) s += xr[i];
    float mu = block_reduce_sum(s, red) * (1.f / EE);
    float vs = 0.f;
    for (int i = threadIdx.x; i < EE; i += 256) { float d = xr[i] - mu; vs += d * d; }
    float var = block_reduce_sum(vs, red) * (1.f / EE);
    float rstd = rsqrtf(var + LEPS);
    ushort* orow = out + (long)t * EE;
    for (int i = threadIdx.x; i < EE; i += 256)
        orow[i] = f2bf((xr[i] - mu) * rstd * g[i] + b[i]);
}

// ---------------- RoPE (first 32 dims of each head), in-place bf16 ----------
__global__ __launch_bounds__(256) void rope_kernel(ushort* __restrict__ q, int nheads, int rowstride) {
    int idx = blockIdx.x * 256 + threadIdx.x;
    int total = TT * nheads * 16;
    if (idx >= total) return;
    int i = idx & 15;
    int h = (idx >> 4) % nheads;
    int t = idx / (16 * nheads);
    float theta = expf(-(float)i * (9.210340371976184f / 16.f));
    float ang = (float)t * theta;
    float c = cosf(ang), s = sinf(ang);
    ushort* p = q + (long)t * rowstride + h * DHEAD;
    float a = bf2f(p[i]), bb = bf2f(p[i + 16]);
    p[i]      = f2bf(a * c - bb * s);
    p[i + 16] = f2bf(bb * c + a * s);
}

// ---------------- bf16 MFMA GEMM: C[M,N] = A[M,K] @ Bt[N,K]^T ----------------
template<bool GELU_ACT, bool ADD, bool OUTBF>
__global__ __launch_bounds__(256) void gemm_bf16(const ushort* __restrict__ A,
                                                 const ushort* __restrict__ B,
                                                 void* __restrict__ Cv,
                                                 int M, int N, int K) {
    __shared__ char lds[16384];   // A tile 8KB @0, B tile 8KB @8192
    const int tid = threadIdx.x;
    const int lane = tid & 63;
    const int w = tid >> 6;
    const int row0 = blockIdx.y * 128, col0 = blockIdx.x * 128;

    const char* ga[2]; const char* gb[2];
    char* la[2]; char* lb[2];
    #pragma unroll
    for (int r = 0; r < 2; ++r) {
        int c = r * 256 + tid;
        ga[r] = (const char*)A + ((long)(row0 + (c >> 2)) * K) * 2 + (c & 3) * 16;
        gb[r] = (const char*)B + ((long)(col0 + (c >> 2)) * K) * 2 + (c & 3) * 16;
        int wc = r * 256 + w * 64;
        la[r] = lds + wc * 16;
        lb[r] = lds + 8192 + wc * 16;
    }

    floatx4 acc[4][4];
    #pragma unroll
    for (int i = 0; i < 4; ++i)
        #pragma unroll
        for (int j = 0; j < 4; ++j) acc[i][j] = {0.f, 0.f, 0.f, 0.f};

    const int mbase = (w >> 1) * 64;
    const int nbase = (w & 1) * 64;
    const int lr = lane & 15;
    const int ko = (lane >> 4) * 16;

    for (int k0 = 0; k0 < K; k0 += 32) {
        #pragma unroll
        for (int r = 0; r < 2; ++r) {
            __builtin_amdgcn_global_load_lds(
                (const __attribute__((address_space(1))) void*)ga[r],
                (__attribute__((address_space(3))) void*)la[r], 16, 0, 0);
            __builtin_amdgcn_global_load_lds(
                (const __attribute__((address_space(1))) void*)gb[r],
                (__attribute__((address_space(3))) void*)lb[r], 16, 0, 0);
            ga[r] += 64; gb[r] += 64;
        }
        __syncthreads();
        short8 af[4], bfr[4];
        #pragma unroll
        for (int i = 0; i < 4; ++i)
            af[i] = *(const short8*)(lds + (mbase + i * 16 + lr) * 64 + ko);
        #pragma unroll
        for (int j = 0; j < 4; ++j)
            bfr[j] = *(const short8*)(lds + 8192 + (nbase + j * 16 + lr) * 64 + ko);
        #pragma unroll
        for (int i = 0; i < 4; ++i)
            #pragma unroll
            for (int j = 0; j < 4; ++j)
                acc[i][j] = __builtin_amdgcn_mfma_f32_16x16x32_bf16(af[i], bfr[j], acc[i][j], 0, 0, 0);
        __syncthreads();
    }

    const int orow = (lane >> 4) * 4;
    const int ocol = lane & 15;
    #pragma unroll
    for (int i = 0; i < 4; ++i) {
        #pragma unroll
        for (int j = 0; j < 4; ++j) {
            #pragma unroll
            for (int r = 0; r < 4; ++r) {
                long off = (long)(row0 + mbase + i * 16 + orow + r) * N
                         + (col0 + nbase + j * 16 + ocol);
                float v = acc[i][j][r];
                if (GELU_ACT) v = 0.5f * v * (1.f + erff(v * 0.70710678118654752f));
                if (OUTBF) {
                    ((ushort*)Cv)[off] = f2bf(v);
                } else {
                    float* C = (float*)Cv;
                    if (ADD) C[off] += v; else C[off] = v;
                }
            }
        }
    }
}

// ---------------- scores = Q @ K^T per head (causal-skip), fp32 out ---------
// A = qkv rows (stride QKVN) at head offset; B = qkv rows at k offset.
__global__ __launch_bounds__(256) void scores_gemm(const ushort* __restrict__ qkv,
                                                   float* __restrict__ scores) {
    __shared__ char lds[16384];
    const int tid = threadIdx.x;
    const int lane = tid & 63;
    const int w = tid >> 6;
    const int col0 = blockIdx.x * 128, row0 = blockIdx.y * 128, h = blockIdx.z;
    if (col0 > row0) return;   // fully-masked causal tile

    const ushort* A = qkv + h * DHEAD;
    const ushort* B = qkv + EE + (h >> 2) * DHEAD;

    const char* ga[2]; const char* gb[2];
    char* la[2]; char* lb[2];
    #pragma unroll
    for (int r = 0; r < 2; ++r) {
        int c = r * 256 + tid;
        ga[r] = (const char*)A + (long)(row0 + (c >> 2)) * QKVN * 2 + (c & 3) * 16;
        gb[r] = (const char*)B + (long)(col0 + (c >> 2)) * QKVN * 2 + (c & 3) * 16;
        int wc = r * 256 + w * 64;
        la[r] = lds + wc * 16;
        lb[r] = lds + 8192 + wc * 16;
    }

    floatx4 acc[4][4];
    #pragma unroll
    for (int i = 0; i < 4; ++i)
        #pragma unroll
        for (int j = 0; j < 4; ++j) acc[i][j] = {0.f, 0.f, 0.f, 0.f};

    const int mbase = (w >> 1) * 64;
    const int nbase = (w & 1) * 64;
    const int lr = lane & 15;
    const int ko = (lane >> 4) * 16;

    for (int k0 = 0; k0 < DHEAD; k0 += 32) {
        #pragma unroll
        for (int r = 0; r < 2; ++r) {
            __builtin_amdgcn_global_load_lds(
                (const __attribute__((address_space(1))) void*)ga[r],
                (__attribute__((address_space(3))) void*)la[r], 16, 0, 0);
            __builtin_amdgcn_global_load_lds(
                (const __attribute__((address_space(1))) void*)gb[r],
                (__attribute__((address_space(3))) void*)lb[r], 16, 0, 0);
            ga[r] += 64; gb[r] += 64;
        }
        __syncthreads();
        short8 af[4], bfr[4];
        #pragma unroll
        for (int i = 0; i < 4; ++i)
            af[i] = *(const short8*)(lds + (mbase + i * 16 + lr) * 64 + ko);
        #pragma unroll
        for (int j = 0; j < 4; ++j)
            bfr[j] = *(const short8*)(lds + 8192 + (nbase + j * 16 + lr) * 64 + ko);
        #pragma unroll
        for (int i = 0; i < 4; ++i)
            #pragma unroll
            for (int j = 0; j < 4; ++j)
                acc[i][j] = __builtin_amdgcn_mfma_f32_16x16x32_bf16(af[i], bfr[j], acc[i][j], 0, 0, 0);
        __syncthreads();
    }

    float* C = scores + (long)h * TT * TT;
    const int orow = (lane >> 4) * 4;
    const int ocol = lane & 15;
    #pragma unroll
    for (int i = 0; i < 4; ++i)
        #pragma unroll
        for (int j = 0; j < 4; ++j)
            #pragma unroll
            for (int r = 0; r < 4; ++r)
                C[(long)(row0 + mbase + i * 16 + orow + r) * TT
                  + (col0 + nbase + j * 16 + ocol)] = acc[i][j][r];
}

// ---------------- softmax + gate threshold; bf16 P written in place ---------
// Reads fp32 row [0..t] into LDS, writes bf16 P (stride-2048-ushort rows).
__global__ __launch_bounds__(256) void softmax_gate_kernel(float* __restrict__ scores,
                                                           const float* __restrict__ gate) {
    __shared__ float sc[TT];
    __shared__ float red[256];
    int h = blockIdx.x;
    int t = blockIdx.y;
    int tid = threadIdx.x;
    float* row = scores + (long)h * TT * TT + (long)t * TT;

    float lmax = -INFINITY;
    for (int s = tid; s <= t; s += 256) {
        float v = row[s] * 0.125f;   // 1/sqrt(DH)
        sc[s] = v;
        lmax = fmaxf(lmax, v);
    }
    float mx = block_reduce_max(lmax, red);
    float lsum = 0.f;
    for (int s = tid; s <= t; s += 256) {
        float e = expf(sc[s] - mx);
        sc[s] = e;
        lsum += e;
    }
    float sum = block_reduce_sum(lsum, red);   // barrier: all fp32 reads done
    float inv = 1.f / sum;
    float thr = 1.f / (1.f + expf(-gate[h]));

    ushort* prow = (ushort*)row;               // alias — safe post-barrier
    for (int s = tid; s < TT; s += 256) {
        float p = (s <= t) ? sc[s] * inv : 0.f;
        p = (p >= thr) ? p : 0.f;
        prow[s] = f2bf(p);
    }
}

// ---------------- V^T: qkv v-part [TT,256] -> VT [256,TT] bf16 --------------
__global__ __launch_bounds__(256) void vtrans_kernel(const ushort* __restrict__ qkv,
                                                     ushort* __restrict__ VT) {
    __shared__ ushort tile[32][33];
    int s0 = blockIdx.x * 32, d0 = blockIdx.y * 32;
    int tx = threadIdx.x & 31, ty = threadIdx.x >> 5;
    for (int i = ty; i < 32; i += 8)
        tile[i][tx] = qkv[(long)(s0 + i) * QKVN + (EE + NKVH * DHEAD) + d0 + tx];
    __syncthreads();
    for (int i = ty; i < 32; i += 8)
        VT[(long)(d0 + i) * TT + s0 + tx] = tile[tx][i];
}

// ---------------- y = P @ V per head: tile 128x64, bf16 out -----------------
__global__ __launch_bounds__(256) void pv_gemm(const float* __restrict__ scores,
                                               const ushort* __restrict__ VT,
                                               ushort* __restrict__ y) {
    __shared__ char lds[12288];   // A 8KB @0, B 4KB @8192
    const int tid = threadIdx.x;
    const int lane = tid & 63;
    const int w = tid >> 6;
    const int row0 = blockIdx.x * 128, h = blockIdx.y;

    const char* Pb = (const char*)(scores + (long)h * TT * TT);  // P rows: 4096B stride, 2048B used
    const char* Bv = (const char*)(VT + (long)(h >> 2) * DHEAD * TT);

    const char* ga[2]; char* la[2];
    #pragma unroll
    for (int r = 0; r < 2; ++r) {
        int c = r * 256 + tid;
        ga[r] = Pb + (long)(row0 + (c >> 2)) * 4096 + (c & 3) * 16;
        la[r] = lds + (r * 256 + w * 64) * 16;
    }
    const char* gb = Bv + (long)(tid >> 2) * 2048 + (tid & 3) * 16;
    char* lb = lds + 8192 + (w * 64) * 16;

    floatx4 acc[2][4];
    #pragma unroll
    for (int i = 0; i < 2; ++i)
        #pragma unroll
        for (int j = 0; j < 4; ++j) acc[i][j] = {0.f, 0.f, 0.f, 0.f};

    const int mbase = w * 32;
    const int lr = lane & 15;
    const int ko = (lane >> 4) * 16;

    for (int k0 = 0; k0 < TT; k0 += 32) {
        #pragma unroll
        for (int r = 0; r < 2; ++r) {
            __builtin_amdgcn_global_load_lds(
                (const __attribute__((address_space(1))) void*)ga[r],
                (__attribute__((address_space(3))) void*)la[r], 16, 0, 0);
            ga[r] += 64;
        }
        __builtin_amdgcn_global_load_lds(
            (const __attribute__((address_space(1))) void*)gb,
            (__attribute__((address_space(3))) void*)lb, 16, 0, 0);
        gb += 64;
        __syncthreads();
        short8 af[2], bfr[4];
        #pragma unroll
        for (int i = 0; i < 2; ++i)
            af[i] = *(const short8*)(lds + (mbase + i * 16 + lr) * 64 + ko);
        #pragma unroll
        for (int j = 0; j < 4; ++j)
            bfr[j] = *(const short8*)(lds + 8192 + (j * 16 + lr) * 64 + ko);
        #pragma unroll
        for (int i = 0; i < 2; ++i)
            #pragma unroll
            for (int j = 0; j < 4; ++j)
                acc[i][j] = __builtin_amdgcn_mfma_f32_16x16x32_bf16(af[i], bfr[j], acc[i][j], 0, 0, 0);
        __syncthreads();
    }

    const int orow = (lane >> 4) * 4;
    const int ocol = lane & 15;
    #pragma unroll
    for (int i = 0; i < 2; ++i)
        #pragma unroll
        for (int j = 0; j < 4; ++j)
            #pragma unroll
            for (int r = 0; r < 4; ++r)
                y[(long)(row0 + mbase + i * 16 + orow + r) * EE
                  + h * DHEAD + j * 16 + ocol] = f2bf(acc[i][j][r]);
}

// ---------------- loss ----------------
__global__ __launch_bounds__(256) void row_loss_kernel(const float* __restrict__ logits,
                                                       const int* __restrict__ targets,
                                                       float* __restrict__ row_loss) {
    __shared__ float red[256];
    int t = blockIdx.x;
    const float* lr = logits + (long)t * VV;
    float lmax = -INFINITY;
    for (int i = threadIdx.x; i < VV; i += 256) lmax = fmaxf(lmax, lr[i]);
    float mx = block_reduce_max(lmax, red);
    float ls = 0.f;
    for (int i = threadIdx.x; i < VV; i += 256) ls += expf(lr[i] - mx);
    float sum = block_reduce_sum(ls, red);
    if (threadIdx.x == 0)
        row_loss[t] = logf(sum) + mx - lr[targets[t]];
}

__global__ __launch_bounds__(256) void final_loss_kernel(const float* __restrict__ row_loss,
                                                         float* __restrict__ out) {
    __shared__ float red[256];
    float s = 0.f;
    for (int i = threadIdx.x; i < TT; i += 256) s += row_loss[i];
    float tot = block_reduce_sum(s, red);
    if (threadIdx.x == 0) out[0] = tot * (1.f / TT);
}

// ---------------- host orchestration ----------------
extern "C" void kernel_launch(void* const* d_in, const int* in_sizes, int n_in,
                              void* d_out, int out_size, void* d_ws, size_t ws_size,
                              hipStream_t stream) {
    const float* embed = (const float*)d_in[0];
    const float* ln1_g = (const float*)d_in[1];
    const float* ln1_b = (const float*)d_in[2];
    const float* Wq    = (const float*)d_in[3];
    const float* Wk    = (const float*)d_in[4];
    const float* Wv    = (const float*)d_in[5];
    const float* Wo    = (const float*)d_in[6];
    const float* gate  = (const float*)d_in[7];
    const float* ln2_g = (const float*)d_in[8];
    const float* ln2_b = (const float*)d_in[9];
    const float* W1    = (const float*)d_in[10];
    const float* W2    = (const float*)d_in[11];
    const float* lnf_g = (const float*)d_in[12];
    const float* lnf_b = (const float*)d_in[13];
    const int*   idx   = (const int*)d_in[14];
    const int*   tgt   = (const int*)d_in[15];
    float* out = (float*)d_out;

    char* p = (char*)d_ws;
    float*  x      = (float*)p;  p += (long)TT * EE * 4;
    ushort* xn     = (ushort*)p; p += (long)TT * EE * 2;
    ushort* qkvb   = (ushort*)p; p += (long)TT * QKVN * 2;
    ushort* y      = (ushort*)p; p += (long)TT * EE * 2;
    ushort* h1     = (ushort*)p; p += (long)TT * FF * 2;
    float*  rls    = (float*)p;  p += (long)TT * 4;
    ushort* VT     = (ushort*)p; p += (long)NKVH * DHEAD * TT * 2;
    float*  scores = (float*)p;  p += (long)NH * TT * TT * 4;
    ushort* wqkvT  = (ushort*)p; p += (long)2 * QKVN * EE * 2;
    ushort* woT    = (ushort*)p; p += (long)2 * EE * EE * 2;
    ushort* w1T    = (ushort*)p; p += (long)2 * FF * EE * 2;
    ushort* w2T    = (ushort*)p; p += (long)2 * EE * FF * 2;
    ushort* embB   = (ushort*)p; p += (long)VV * EE * 2;

    // ---- prep: bf16 conversions / transposes ----
    convert_bf16_kernel<<<((long)VV * EE / 4 + 255) / 256, 256, 0, stream>>>(embed, embB, (long)VV * EE / 4);
    for (int l = 0; l < 2; ++l) {
        transpose_bf16_kernel<<<dim3(EE / 32, EE / 32), 256, 0, stream>>>(
            Wq + (long)l * EE * EE, wqkvT + (long)l * QKVN * EE, EE, EE);
        transpose_bf16_kernel<<<dim3(NKVH * DHEAD / 32, EE / 32), 256, 0, stream>>>(
            Wk + (long)l * EE * NKVH * DHEAD, wqkvT + (long)l * QKVN * EE + (long)EE * EE, NKVH * DHEAD, EE);
        transpose_bf16_kernel<<<dim3(NKVH * DHEAD / 32, EE / 32), 256, 0, stream>>>(
            Wv + (long)l * EE * NKVH * DHEAD, wqkvT + (long)l * QKVN * EE + (long)(EE + NKVH * DHEAD) * EE, NKVH * DHEAD, EE);
        transpose_bf16_kernel<<<dim3(EE / 32, EE / 32), 256, 0, stream>>>(
            Wo + (long)l * EE * EE, woT + (long)l * EE * EE, EE, EE);
        transpose_bf16_kernel<<<dim3(FF / 32, EE / 32), 256, 0, stream>>>(
            W1 + (long)l * EE * FF, w1T + (long)l * FF * EE, FF, EE);
        transpose_bf16_kernel<<<dim3(EE / 32, FF / 32), 256, 0, stream>>>(
            W2 + (long)l * FF * EE, w2T + (long)l * EE * FF, EE, FF);
    }

    gather_kernel<<<TT, 256, 0, stream>>>(embed, idx, x);

    for (int r = 0; r < 2; ++r) {
        for (int l = 0; l < 2; ++l) {
            ln_kernel<<<TT, 256, 0, stream>>>(x, ln1_g + l * EE, ln1_b + l * EE, xn);
            gemm_bf16<false, false, true><<<dim3(QKVN / 128, TT / 128), 256, 0, stream>>>(
                xn, wqkvT + (long)l * QKVN * EE, qkvb, TT, QKVN, EE);
            rope_kernel<<<(TT * NH * 16 + 255) / 256, 256, 0, stream>>>(qkvb, NH, QKVN);
            rope_kernel<<<(TT * NKVH * 16 + 255) / 256, 256, 0, stream>>>(qkvb + EE, NKVH, QKVN);
            vtrans_kernel<<<dim3(TT / 32, NKVH * DHEAD / 32), 256, 0, stream>>>(qkvb, VT);
            scores_gemm<<<dim3(TT / 128, TT / 128, NH), 256, 0, stream>>>(qkvb, scores);
            softmax_gate_kernel<<<dim3(NH, TT), 256, 0, stream>>>(scores, gate + l * NH);
            pv_gemm<<<dim3(TT / 128, NH), 256, 0, stream>>>(scores, VT, y);
            gemm_bf16<false, true, false><<<dim3(EE / 128, TT / 128), 256, 0, stream>>>(
                y, woT + (long)l * EE * EE, x, TT, EE, EE);

            ln_kernel<<<TT, 256, 0, stream>>>(x, ln2_g + l * EE, ln2_b + l * EE, xn);
            gemm_bf16<true, false, true><<<dim3(FF / 128, TT / 128), 256, 0, stream>>>(
                xn, w1T + (long)l * FF * EE, h1, TT, FF, EE);
            gemm_bf16<false, true, false><<<dim3(EE / 128, TT / 128), 256, 0, stream>>>(
                h1, w2T + (long)l * EE * FF, x, TT, EE, FF);
        }
    }

    ln_kernel<<<TT, 256, 0, stream>>>(x, lnf_g, lnf_b, xn);
    gemm_bf16<false, false, false><<<dim3(VV / 128, TT / 128), 256, 0, stream>>>(
        xn, embB, out, TT, VV, EE);

    row_loss_kernel<<<TT, 256, 0, stream>>>(out, tgt, rls);
    final_loss_kernel<<<1, 256, 0, stream>>>(rls, out + (long)TT * VV);
}